// Round 2
// baseline (46.158 us; speedup 1.0000x reference)
//
#include <hip/hip_runtime.h>

// CorrLookup: RAFT-style correlation-pyramid lookup.
// B=8, H=96, W=256, N=196608, R=4, K=9 taps, 4 levels, Wi = 256>>lvl.
// One thread per (pixel, level): blockIdx.y = level (uniform per block).
// The 10-tap span [ib-4, ib+5] is read as 4 aligned float4 chunks; chunk
// validity is exact (bounds are multiples of 4, rows are 16B-aligned), which
// preserves the zeros-padding semantics of OOB taps.

#define RADIUS 4
#define KTAPS 9

__global__ __launch_bounds__(256) void corr_lookup_kernel(
    const float* __restrict__ corr0,
    const float* __restrict__ corr1,
    const float* __restrict__ corr2,
    const float* __restrict__ corr3,
    const float* __restrict__ flow,
    float* __restrict__ out,
    int HW, int N)
{
    int n = blockIdx.x * blockDim.x + threadIdx.x;
    if (n >= N) return;
    const int lvl = blockIdx.y;          // wave-uniform

    int b   = n / HW;
    int rem = n - b * HW;

    // flow layout: (B, 2, H, W); channel 0 = disparity
    float disp = flow[(size_t)b * 2 * HW + rem];

    const float* base = (lvl == 0) ? corr0 : (lvl == 1) ? corr1
                      : (lvl == 2) ? corr2 : corr3;
    const int Wi = 256 >> lvl;

    float t  = disp * (1.0f / (float)(1 << lvl));   // exact pow2 scale
    float fb = floorf(t);
    float w  = t - fb;                  // shared fractional weight for all taps
    int   ib = (int)fb;

    int s  = ib - RADIUS;               // first tap index (may be negative)
    int o  = s & 3;                     // offset of tap 0 within chunk c0
    int c0 = s >> 2;                    // aligned float4 chunk index (floor div)
    int Wc = Wi >> 2;                   // row length in float4 chunks

    const float4* row4 = (const float4*)(base + (size_t)n * (size_t)Wi);
    const float4 z = make_float4(0.f, 0.f, 0.f, 0.f);

    float4 A = (c0 + 0 >= 0 && c0 + 0 < Wc) ? row4[c0 + 0] : z;
    float4 Bq= (c0 + 1 >= 0 && c0 + 1 < Wc) ? row4[c0 + 1] : z;
    float4 C = (c0 + 2 >= 0 && c0 + 2 < Wc) ? row4[c0 + 2] : z;
    float4 D = (c0 + 3 >= 0 && c0 + 3 < Wc) ? row4[c0 + 3] : z;

    // 16 elements covering taps 0..9 at offset o; constant-indexed only.
    float e[16] = {A.x, A.y, A.z, A.w,  Bq.x, Bq.y, Bq.z, Bq.w,
                   C.x, C.y, C.z, C.w,  D.x,  D.y,  D.z,  D.w};

    // out layout: (B, 36, H, W)
    size_t ob = (size_t)b * 36 * HW + (size_t)(lvl * KTAPS) * HW + (size_t)rem;

#pragma unroll
    for (int k = 0; k < KTAPS; ++k) {
        // v[k] = e[o + k], v[k+1] = e[o + k + 1]; o in {0..3}, k compile-time
        float vk  = (o == 0) ? e[k + 0] : (o == 1) ? e[k + 1]
                  : (o == 2) ? e[k + 2] : e[k + 3];
        float vk1 = (o == 0) ? e[k + 1] : (o == 1) ? e[k + 2]
                  : (o == 2) ? e[k + 3] : e[k + 4];
        out[ob + (size_t)k * HW] = (1.0f - w) * vk + w * vk1;
    }
}

extern "C" void kernel_launch(void* const* d_in, const int* in_sizes, int n_in,
                              void* d_out, int out_size, void* d_ws, size_t ws_size,
                              hipStream_t stream)
{
    const float* corr0 = (const float*)d_in[0];
    const float* corr1 = (const float*)d_in[1];
    const float* corr2 = (const float*)d_in[2];
    const float* corr3 = (const float*)d_in[3];
    const float* flow  = (const float*)d_in[4];
    float* out = (float*)d_out;

    const int N  = in_sizes[4] / 2;   // flow is (B,2,H,W)
    const int B  = 8;
    const int HW = N / B;             // 96*256 = 24576

    dim3 block(256);
    dim3 grid((N + 255) / 256, 4);    // y = pyramid level (uniform per block)
    hipLaunchKernelGGL(corr_lookup_kernel, grid, block, 0, stream,
                       corr0, corr1, corr2, corr3, flow, out, HW, N);
}

// Round 3
// 40.206 us; speedup vs baseline: 1.1480x; 1.1480x over previous
//
#include <hip/hip_runtime.h>

// CorrLookup: RAFT-style correlation-pyramid lookup.
// B=8, H=96, W=256, N=B*H*W=196608, R=4, K=9, 4 levels, Wi = 256>>lvl.
// One thread per pixel, all 4 levels (round-1 proven structure).
// Round-3 change: ALL loads issued before ALL stores (single read burst,
// then single write burst per thread) + nontemporal stores for out.

#define RADIUS 4
#define KTAPS 9

__global__ __launch_bounds__(256) void corr_lookup_kernel(
    const float* __restrict__ corr0,
    const float* __restrict__ corr1,
    const float* __restrict__ corr2,
    const float* __restrict__ corr3,
    const float* __restrict__ flow,
    float* __restrict__ out,
    int HW, int N)
{
    int n = blockIdx.x * blockDim.x + threadIdx.x;
    if (n >= N) return;

    int b   = n / HW;          // batch
    int rem = n - b * HW;      // h*W + w within the image

    // flow layout: (B, 2, H, W); channel 0 = disparity
    float disp = flow[(size_t)b * 2 * HW + rem];

    const float* const corrs[4] = {corr0, corr1, corr2, corr3};

    float v[4][KTAPS + 1];     // all taps, all levels — loaded before any store
    float wgt[4];

    // ---- read burst: 40 bounds-checked tap loads (all independent) ----
#pragma unroll
    for (int lvl = 0; lvl < 4; ++lvl) {
        const int Wi = 256 >> lvl;
        const float scale = 1.0f / (float)(1 << lvl);   // exact pow2
        float t  = disp * scale;
        float fb = floorf(t);
        wgt[lvl] = t - fb;                 // shared fractional weight
        int   ib = (int)fb;

        const float* row = corrs[lvl] + (size_t)n * (size_t)Wi;
#pragma unroll
        for (int j = 0; j <= KTAPS; ++j) {
            int idx = ib - RADIUS + j;
            v[lvl][j] = (idx >= 0 && idx < Wi) ? row[idx] : 0.0f;
        }
    }

    // ---- write burst: 36 coalesced nontemporal stores ----
    // out layout: (B, 36, H, W)
    size_t out_base = (size_t)b * 36 * HW + (size_t)rem;
#pragma unroll
    for (int lvl = 0; lvl < 4; ++lvl) {
        float w = wgt[lvl];
#pragma unroll
        for (int k = 0; k < KTAPS; ++k) {
            float val = (1.0f - w) * v[lvl][k] + w * v[lvl][k + 1];
            __builtin_nontemporal_store(
                val, &out[out_base + (size_t)(lvl * KTAPS + k) * (size_t)HW]);
        }
    }
}

extern "C" void kernel_launch(void* const* d_in, const int* in_sizes, int n_in,
                              void* d_out, int out_size, void* d_ws, size_t ws_size,
                              hipStream_t stream)
{
    const float* corr0 = (const float*)d_in[0];
    const float* corr1 = (const float*)d_in[1];
    const float* corr2 = (const float*)d_in[2];
    const float* corr3 = (const float*)d_in[3];
    const float* flow  = (const float*)d_in[4];
    float* out = (float*)d_out;

    const int N  = in_sizes[4] / 2;   // flow is (B,2,H,W)
    const int B  = 8;
    const int HW = N / B;             // 96*256 = 24576

    dim3 block(256);
    dim3 grid((N + 255) / 256);
    hipLaunchKernelGGL(corr_lookup_kernel, grid, block, 0, stream,
                       corr0, corr1, corr2, corr3, flow, out, HW, N);
}

// Round 4
// 32.156 us; speedup vs baseline: 1.4354x; 1.2503x over previous
//
#include <hip/hip_runtime.h>

// CorrLookup: RAFT-style correlation-pyramid lookup.
// B=8, H=96, W=256, N=B*H*W=196608, R=4, K=9, 4 levels, Wi = 256>>lvl.
// One thread per pixel (round-1 proven structure).
// Round-4 change: clamp-then-load instead of predicated load. The tap load
// is always in-bounds (index clamped to [0, Wi-1]) so the compiler emits an
// unconditional global_load_dword; zeros-padding is applied afterwards with
// a single cndmask per tap ((unsigned)idx < Wi). No exec-mask manipulation
// around the 40 gather loads.

#define RADIUS 4
#define KTAPS 9

__global__ __launch_bounds__(256) void corr_lookup_kernel(
    const float* __restrict__ corr0,
    const float* __restrict__ corr1,
    const float* __restrict__ corr2,
    const float* __restrict__ corr3,
    const float* __restrict__ flow,
    float* __restrict__ out,
    int HW, int N)
{
    int n = blockIdx.x * blockDim.x + threadIdx.x;
    if (n >= N) return;

    int b   = n / HW;          // batch
    int rem = n - b * HW;      // h*W + w within the image

    // flow layout: (B, 2, H, W); channel 0 = disparity
    float disp = flow[(size_t)b * 2 * HW + rem];

    const float* const corrs[4] = {corr0, corr1, corr2, corr3};

    // out layout: (B, 36, H, W)
    size_t out_base = (size_t)b * 36 * HW + (size_t)rem;

#pragma unroll
    for (int lvl = 0; lvl < 4; ++lvl) {
        const int Wi = 256 >> lvl;
        const float scale = 1.0f / (float)(1 << lvl);   // exact pow2
        float t  = disp * scale;
        float fb = floorf(t);
        float w  = t - fb;          // shared fractional weight for all 9 taps
        int   ib = (int)fb;

        const float* row = corrs[lvl] + (size_t)n * (size_t)Wi;

        // contiguous span ib-4 .. ib+5; unconditional clamped loads,
        // zeros-padding applied via value select (no load predication).
        float v[KTAPS + 1];
#pragma unroll
        for (int j = 0; j <= KTAPS; ++j) {
            int idx  = ib - RADIUS + j;
            int idxc = min(max(idx, 0), Wi - 1);        // v_med3-style clamp
            float vr = row[idxc];                       // always in-bounds
            v[j] = ((unsigned)idx < (unsigned)Wi) ? vr : 0.0f;  // 1 cndmask
        }

#pragma unroll
        for (int k = 0; k < KTAPS; ++k) {
            float val = (1.0f - w) * v[k] + w * v[k + 1];
            out[out_base + (size_t)(lvl * KTAPS + k) * (size_t)HW] = val;
        }
    }
}

extern "C" void kernel_launch(void* const* d_in, const int* in_sizes, int n_in,
                              void* d_out, int out_size, void* d_ws, size_t ws_size,
                              hipStream_t stream)
{
    const float* corr0 = (const float*)d_in[0];
    const float* corr1 = (const float*)d_in[1];
    const float* corr2 = (const float*)d_in[2];
    const float* corr3 = (const float*)d_in[3];
    const float* flow  = (const float*)d_in[4];
    float* out = (float*)d_out;

    const int N  = in_sizes[4] / 2;   // flow is (B,2,H,W)
    const int B  = 8;
    const int HW = N / B;             // 96*256 = 24576

    dim3 block(256);
    dim3 grid((N + 255) / 256);
    hipLaunchKernelGGL(corr_lookup_kernel, grid, block, 0, stream,
                       corr0, corr1, corr2, corr3, flow, out, HW, N);
}

// Round 5
// 28.084 us; speedup vs baseline: 1.6436x; 1.1450x over previous
//
#include <hip/hip_runtime.h>

// CorrLookup: RAFT-style correlation-pyramid lookup.
// B=8, H=96, W=256, N=B*H*W=196608, R=4, K=9, 4 levels, Wi = 256>>lvl.
// One thread per pixel (round-4 proven structure: clamped unconditional
// loads, value-level zeroing, no load predication).
// Round-5 change: the 10-tap span [s, s+9] (s = ib-4) is fetched as 4
// ALIGNED float4 chunks (chunk index clamped to [0, Wc-1], loads always
// in-bounds -> plain global_load_dwordx4). Taps are extracted with a
// 3-cndmask offset select (o = s&3) + 1 validity cndmask per tap.
// 41 -> 17 VMEM requests per thread, same bytes-per-line fetched.

#define RADIUS 4
#define KTAPS 9

__global__ __launch_bounds__(256) void corr_lookup_kernel(
    const float* __restrict__ corr0,
    const float* __restrict__ corr1,
    const float* __restrict__ corr2,
    const float* __restrict__ corr3,
    const float* __restrict__ flow,
    float* __restrict__ out,
    int HW, int N)
{
    int n = blockIdx.x * blockDim.x + threadIdx.x;
    if (n >= N) return;

    int b   = n / HW;          // batch
    int rem = n - b * HW;      // h*W + w within the image

    // flow layout: (B, 2, H, W); channel 0 = disparity
    float disp = flow[(size_t)b * 2 * HW + rem];

    const float* const corrs[4] = {corr0, corr1, corr2, corr3};

    // out layout: (B, 36, H, W)
    size_t out_base = (size_t)b * 36 * HW + (size_t)rem;

#pragma unroll
    for (int lvl = 0; lvl < 4; ++lvl) {
        const int Wi = 256 >> lvl;
        const int Wc = Wi >> 2;                          // row length in float4
        const float scale = 1.0f / (float)(1 << lvl);    // exact pow2
        float t  = disp * scale;
        float fb = floorf(t);
        float w  = t - fb;           // shared fractional weight for all 9 taps
        int   ib = (int)fb;

        int s  = ib - RADIUS;        // first tap index (may be negative)
        int o  = s & 3;              // tap-0 offset within first chunk
        int c0 = s >> 2;             // floor(s/4): first aligned chunk

        const float4* row4 = (const float4*)(corrs[lvl] + (size_t)n * (size_t)Wi);

        // 4 aligned chunks cover taps s..s+9 for any o in {0..3}.
        // Clamped, unconditional loads (no exec-mask predication).
        float4 q0, q1, q2, q3;
        {
            int cA = min(max(c0 + 0, 0), Wc - 1);
            int cB = min(max(c0 + 1, 0), Wc - 1);
            int cC = min(max(c0 + 2, 0), Wc - 1);
            int cD = min(max(c0 + 3, 0), Wc - 1);
            q0 = row4[cA]; q1 = row4[cB]; q2 = row4[cC]; q3 = row4[cD];
        }
        float e[16] = {q0.x, q0.y, q0.z, q0.w,  q1.x, q1.y, q1.z, q1.w,
                       q2.x, q2.y, q2.z, q2.w,  q3.x, q3.y, q3.z, q3.w};

        // Offset-select conditions computed once, reused for all taps.
        bool o0 = (o == 0), o1 = (o == 1), o2 = (o == 2);

        float v[KTAPS + 1];
#pragma unroll
        for (int j = 0; j <= KTAPS; ++j) {
            float sel = o0 ? e[j + 0] : o1 ? e[j + 1] : o2 ? e[j + 2] : e[j + 3];
            v[j] = ((unsigned)(s + j) < (unsigned)Wi) ? sel : 0.0f;
        }

#pragma unroll
        for (int k = 0; k < KTAPS; ++k) {
            float val = (1.0f - w) * v[k] + w * v[k + 1];
            out[out_base + (size_t)(lvl * KTAPS + k) * (size_t)HW] = val;
        }
    }
}

extern "C" void kernel_launch(void* const* d_in, const int* in_sizes, int n_in,
                              void* d_out, int out_size, void* d_ws, size_t ws_size,
                              hipStream_t stream)
{
    const float* corr0 = (const float*)d_in[0];
    const float* corr1 = (const float*)d_in[1];
    const float* corr2 = (const float*)d_in[2];
    const float* corr3 = (const float*)d_in[3];
    const float* flow  = (const float*)d_in[4];
    float* out = (float*)d_out;

    const int N  = in_sizes[4] / 2;   // flow is (B,2,H,W)
    const int B  = 8;
    const int HW = N / B;             // 96*256 = 24576

    dim3 block(256);
    dim3 grid((N + 255) / 256);
    hipLaunchKernelGGL(corr_lookup_kernel, grid, block, 0, stream,
                       corr0, corr1, corr2, corr3, flow, out, HW, N);
}

// Round 6
// 27.114 us; speedup vs baseline: 1.7024x; 1.0358x over previous
//
#include <hip/hip_runtime.h>

// CorrLookup: RAFT-style correlation-pyramid lookup.
// B=8, H=96, W=256, N=B*H*W=196608, R=4, K=9, 4 levels, Wi = 256>>lvl.
// One thread per pixel. Round-6 change: fetch 3 aligned float4 chunks
// (48 B) + 1 scalar tail instead of 4 chunks (64 B). Element 12 is only
// needed when o==3; for o<3 the tail load's ADDRESS is redirected (one
// cndmask) to element 11, which lives in an already-fetched line -> no
// extra HBM line. All loads remain unconditional & clamped (no exec-mask
// predication -- the R4 lesson).

#define RADIUS 4
#define KTAPS 9

__global__ __launch_bounds__(256) void corr_lookup_kernel(
    const float* __restrict__ corr0,
    const float* __restrict__ corr1,
    const float* __restrict__ corr2,
    const float* __restrict__ corr3,
    const float* __restrict__ flow,
    float* __restrict__ out,
    int HW, int N)
{
    int n = blockIdx.x * blockDim.x + threadIdx.x;
    if (n >= N) return;

    int b   = n / HW;          // batch
    int rem = n - b * HW;      // h*W + w within the image

    // flow layout: (B, 2, H, W); channel 0 = disparity
    float disp = flow[(size_t)b * 2 * HW + rem];

    const float* const corrs[4] = {corr0, corr1, corr2, corr3};

    // out layout: (B, 36, H, W)
    size_t out_base = (size_t)b * 36 * HW + (size_t)rem;

#pragma unroll
    for (int lvl = 0; lvl < 4; ++lvl) {
        const int Wi = 256 >> lvl;
        const int Wc = Wi >> 2;                          // row length in float4
        const float scale = 1.0f / (float)(1 << lvl);    // exact pow2
        float t  = disp * scale;
        float fb = floorf(t);
        float w  = t - fb;           // shared fractional weight for all 9 taps
        int   ib = (int)fb;

        int s  = ib - RADIUS;        // first tap index (may be negative)
        int o  = s & 3;              // tap-0 offset within first chunk
        int c0 = s >> 2;             // floor(s/4): first aligned chunk

        const float* rowp  = corrs[lvl] + (size_t)n * (size_t)Wi;
        const float4* row4 = (const float4*)rowp;

        // 3 aligned chunks cover elements 0..11 of the 13-element window;
        // element 12 (needed only when o==3) comes from a scalar tail load
        // whose address is redirected to element 11 when o<3.
        int cA = min(max(c0 + 0, 0), Wc - 1);
        int cB = min(max(c0 + 1, 0), Wc - 1);
        int cC = min(max(c0 + 2, 0), Wc - 1);
        float4 q0 = row4[cA];
        float4 q1 = row4[cB];
        float4 q2 = row4[cC];
        int tail_idx = (c0 << 2) + ((o == 3) ? 12 : 11);
        tail_idx = min(max(tail_idx, 0), Wi - 1);
        float tail = rowp[tail_idx];

        float e[13] = {q0.x, q0.y, q0.z, q0.w,
                       q1.x, q1.y, q1.z, q1.w,
                       q2.x, q2.y, q2.z, q2.w, tail};

        bool o0 = (o == 0), o1 = (o == 1), o2 = (o == 2);

        float v[KTAPS + 1];
#pragma unroll
        for (int j = 0; j <= KTAPS; ++j) {
            float sel = o0 ? e[j + 0] : o1 ? e[j + 1] : o2 ? e[j + 2] : e[j + 3];
            v[j] = ((unsigned)(s + j) < (unsigned)Wi) ? sel : 0.0f;
        }

#pragma unroll
        for (int k = 0; k < KTAPS; ++k) {
            float val = (1.0f - w) * v[k] + w * v[k + 1];
            out[out_base + (size_t)(lvl * KTAPS + k) * (size_t)HW] = val;
        }
    }
}

extern "C" void kernel_launch(void* const* d_in, const int* in_sizes, int n_in,
                              void* d_out, int out_size, void* d_ws, size_t ws_size,
                              hipStream_t stream)
{
    const float* corr0 = (const float*)d_in[0];
    const float* corr1 = (const float*)d_in[1];
    const float* corr2 = (const float*)d_in[2];
    const float* corr3 = (const float*)d_in[3];
    const float* flow  = (const float*)d_in[4];
    float* out = (float*)d_out;

    const int N  = in_sizes[4] / 2;   // flow is (B,2,H,W)
    const int B  = 8;
    const int HW = N / B;             // 96*256 = 24576

    dim3 block(256);
    dim3 grid((N + 255) / 256);
    hipLaunchKernelGGL(corr_lookup_kernel, grid, block, 0, stream,
                       corr0, corr1, corr2, corr3, flow, out, HW, N);
}